// Round 10
// baseline (187.129 us; speedup 1.0000x reference)
//
#include <hip/hip_runtime.h>
#include <hip/hip_bf16.h>

// ---------------------------------------------------------------------------
// CollapsedPBFA: x->(qkv GEMM)->cheb-kernelized linear attention->out GEMM
// R10: gemm1 keeps R9 geometry (256x256, BK=64, quadrant snake, distance-2
//      half-tile staging) but adopts the m201 8-phase sync skeleton:
//      {ds_read -> stage -> barrier -> lgkmcnt(0) -> MFMA -> barrier} per
//      phase, one counted vmcnt per K-tile at phase-3 end.
//      gemm2 keeps the R8 256x128 kernel. kv/attn unchanged.
// ---------------------------------------------------------------------------

#define SEQ    4096
#define BATCH  2
#define DMODEL 1024
#define NH     16
#define DH     64
#define MD     11
#define NCH    8
#define CHUNK  512   // SEQ / NCH

typedef __attribute__((ext_vector_type(8)))  short  short8;
typedef __attribute__((ext_vector_type(4)))  short  s16x4;
typedef __attribute__((ext_vector_type(8)))  __bf16 bf16x8;
typedef __attribute__((ext_vector_type(4)))  float  f32x4;

__device__ __forceinline__ short f2bf(float f) {
  union { float f; unsigned u; } c; c.f = f;
  unsigned r = c.u + 0x7FFFu + ((c.u >> 16) & 1u);
  return (short)(r >> 16);
}
__device__ __forceinline__ float bf2f(short h) {
  union { unsigned u; float f; } c; c.u = ((unsigned)(unsigned short)h) << 16;
  return c.f;
}

__device__ __forceinline__ f32x4 mfma16(short8 a, short8 b, f32x4 c) {
  return __builtin_amdgcn_mfma_f32_16x16x32_bf16(
      __builtin_bit_cast(bf16x8, a), __builtin_bit_cast(bf16x8, b), c, 0, 0, 0);
}

typedef const __attribute__((address_space(1))) void* gvp;
typedef __attribute__((address_space(3))) void* lvp;
__device__ __forceinline__ void gload16(const void* g, void* l) {
  __builtin_amdgcn_global_load_lds((gvp)g, (lvp)l, 16, 0, 0);
}

// ---------------------------------------------------------------------------
__global__ __launch_bounds__(256) void to_bf16(const float* __restrict__ src,
                                               short* __restrict__ dst, int n4) {
  int i = blockIdx.x * 256 + threadIdx.x;
  if (i < n4) {
    f32x4 v = ((const f32x4*)src)[i];
    s16x4 o;
#pragma unroll
    for (int q = 0; q < 4; ++q) o[q] = f2bf(v[q]);
    ((s16x4*)dst)[i] = o;
  }
}

// ---------------------------------------------------------------------------
// gemm256sq: C[M][N] = A[M][K] * B[N][K]^T, 256x256 tile, BK=64, 512 thr,
// 8 waves (wm=w>>2, wn=w&3), per-wave output 128x64. 8-phase-style schedule:
// per K-tile, 4 phases = quadrants (00,01,11,10); each phase:
//   {ds_read frag subtile; stage one half-tile; s_barrier; lgkmcnt(0);
//    setprio(1); 16 MFMA; setprio(0); s_barrier}
// Distance-2 staging: tile U stages A1(U+1),B0(U+1),A0(U+2),B1(U+2); single
// counted vmcnt(4) per tile at phase-3 end (vmcnt(0) only at U=NT-2).
// Requires: M%256==0, N%256==0, K%64==0, K/64>=3, grid%8==0.
// ---------------------------------------------------------------------------
template <typename SC>
__global__ __launch_bounds__(512, 2) void gemm256sq(const short* __restrict__ A,
                                                    const short* __restrict__ B,
                                                    SC* __restrict__ C,
                                                    int M, int N, int K) {
  __shared__ short lds[65536];

  const int tid  = threadIdx.x;
  const int lane = tid & 63;
  const int w    = tid >> 6;     // 0..7
  const int wm   = w >> 2;       // 0..1
  const int wn   = w & 3;        // 0..3
  const int g    = lane >> 4;    // 0..3
  const int r    = lane & 15;    // 0..15

  const int nbn = N >> 8;
  int bid = blockIdx.x;
  {
    const int cpx = gridDim.x >> 3;
    bid = (bid & 7) * cpx + (bid >> 3);
  }
  const int brow = (bid / nbn) << 8;
  const int bcol = (bid % nbn) << 8;
  const int NT   = K >> 6;

  // staging lane geometry (verified 0-conflict): issue covers 64 rows x 64 cols
  const int lr    = lane >> 3;               // 0..7
  const int lc    = lane & 7;
  const int swz_w = ((w * 8 + lr) >> 1) & 7;
  const int cgs   = (lc ^ swz_w) * 8;        // pre-swizzled global col (shorts)
  const int swz_r = (r >> 1) & 7;            // read-side swizzle

  f32x4 acc[2][4][2][2];  // [qr][mi][qc][ni]
#pragma unroll
  for (int a = 0; a < 2; ++a)
#pragma unroll
    for (int b = 0; b < 4; ++b)
#pragma unroll
      for (int c = 0; c < 2; ++c)
#pragma unroll
        for (int d = 0; d < 2; ++d) acc[a][b][c][d] = (f32x4){0.f, 0.f, 0.f, 0.f};

  auto SA = [&](int d, int half, int t) {
#pragma unroll
    for (int sub = 0; sub < 2; ++sub) {
      const int rowb = half * 128 + sub * 64;
      const short* ga = A + (size_t)(brow + rowb + w * 8 + lr) * K + (t << 6) + cgs;
      gload16(ga, &lds[d * 16384 + (rowb + w * 8) * 64]);
    }
  };
  auto SB = [&](int d, int half, int t) {
#pragma unroll
    for (int sub = 0; sub < 2; ++sub) {
      const int colb = half * 128 + sub * 64;
      const short* gb = B + (size_t)(bcol + colb + w * 8 + lr) * K + (t << 6) + cgs;
      gload16(gb, &lds[32768 + d * 16384 + (colb + w * 8) * 64]);
    }
  };
  auto RA = [&](int d, int qr, int mi, int ks) -> short8 {
    const int row = wm * 64 + qr * 128 + mi * 16 + r;
    return *(const short8*)&lds[d * 16384 + row * 64 + ((ks * 4 + g) ^ swz_r) * 8];
  };
  auto RB = [&](int d, int qc, int ni, int ks) -> short8 {
    const int col = wn * 32 + qc * 128 + ni * 16 + r;
    return *(const short8*)&lds[32768 + d * 16384 + col * 64 + ((ks * 4 + g) ^ swz_r) * 8];
  };

  // ---- prologue: tile 0 complete + A0(1), B1(1); counted wait, no drain ----
  SA(0, 0, 0);
  SA(0, 1, 0);
  SB(0, 0, 0);
  SB(0, 1, 0);
  SA(1, 0, 1);
  SB(1, 1, 1);
  asm volatile("s_waitcnt vmcnt(4)" ::: "memory");   // tile 0's 4 halves landed
  __builtin_amdgcn_s_barrier();                      // cross-wave visibility

  short8 av[4][2], bv[2][2];

  for (int U = 0; U < NT; ++U) {
    const int d  = U & 1;
    const int dn = d ^ 1;
    const bool s1 = (U + 1 < NT), s2 = (U + 2 < NT);

    // ===== phase 0: quadrant (0,0) — reads A[qr0](8) + B[qc0](4) =====
#pragma unroll
    for (int mi = 0; mi < 4; ++mi)
#pragma unroll
      for (int ks = 0; ks < 2; ++ks) av[mi][ks] = RA(d, 0, mi, ks);
#pragma unroll
    for (int ni = 0; ni < 2; ++ni)
#pragma unroll
      for (int ks = 0; ks < 2; ++ks) bv[ni][ks] = RB(d, 0, ni, ks);
    if (s1) SA(dn, 1, U + 1);
    __builtin_amdgcn_sched_barrier(0);
    __builtin_amdgcn_s_barrier();
    asm volatile("s_waitcnt lgkmcnt(0)" ::: "memory");
    __builtin_amdgcn_sched_barrier(0);
    __builtin_amdgcn_s_setprio(1);
#pragma unroll
    for (int mi = 0; mi < 4; ++mi)
#pragma unroll
      for (int ni = 0; ni < 2; ++ni) {
        acc[0][mi][0][ni] = mfma16(av[mi][0], bv[ni][0], acc[0][mi][0][ni]);
        acc[0][mi][0][ni] = mfma16(av[mi][1], bv[ni][1], acc[0][mi][0][ni]);
      }
    __builtin_amdgcn_s_setprio(0);
    __builtin_amdgcn_s_barrier();

    // ===== phase 1: quadrant (0,1) — reads B[qc1](4), reuse av =====
#pragma unroll
    for (int ni = 0; ni < 2; ++ni)
#pragma unroll
      for (int ks = 0; ks < 2; ++ks) bv[ni][ks] = RB(d, 1, ni, ks);
    if (s1) SB(dn, 0, U + 1);
    __builtin_amdgcn_sched_barrier(0);
    __builtin_amdgcn_s_barrier();
    asm volatile("s_waitcnt lgkmcnt(0)" ::: "memory");
    __builtin_amdgcn_sched_barrier(0);
    __builtin_amdgcn_s_setprio(1);
#pragma unroll
    for (int mi = 0; mi < 4; ++mi)
#pragma unroll
      for (int ni = 0; ni < 2; ++ni) {
        acc[0][mi][1][ni] = mfma16(av[mi][0], bv[ni][0], acc[0][mi][1][ni]);
        acc[0][mi][1][ni] = mfma16(av[mi][1], bv[ni][1], acc[0][mi][1][ni]);
      }
    __builtin_amdgcn_s_setprio(0);
    __builtin_amdgcn_s_barrier();

    // ===== phase 2: quadrant (1,1) — reads A[qr1](8), reuse bv =====
#pragma unroll
    for (int mi = 0; mi < 4; ++mi)
#pragma unroll
      for (int ks = 0; ks < 2; ++ks) av[mi][ks] = RA(d, 1, mi, ks);
    if (s2) SA(d, 0, U + 2);
    __builtin_amdgcn_sched_barrier(0);
    __builtin_amdgcn_s_barrier();
    asm volatile("s_waitcnt lgkmcnt(0)" ::: "memory");
    __builtin_amdgcn_sched_barrier(0);
    __builtin_amdgcn_s_setprio(1);
#pragma unroll
    for (int mi = 0; mi < 4; ++mi)
#pragma unroll
      for (int ni = 0; ni < 2; ++ni) {
        acc[1][mi][1][ni] = mfma16(av[mi][0], bv[ni][0], acc[1][mi][1][ni]);
        acc[1][mi][1][ni] = mfma16(av[mi][1], bv[ni][1], acc[1][mi][1][ni]);
      }
    __builtin_amdgcn_s_setprio(0);
    __builtin_amdgcn_s_barrier();

    // ===== phase 3: quadrant (1,0) — re-reads B[qc0](4), reuse av =====
#pragma unroll
    for (int ni = 0; ni < 2; ++ni)
#pragma unroll
      for (int ks = 0; ks < 2; ++ks) bv[ni][ks] = RB(d, 0, ni, ks);
    if (s2) SB(d, 1, U + 2);
    __builtin_amdgcn_sched_barrier(0);
    __builtin_amdgcn_s_barrier();
    asm volatile("s_waitcnt lgkmcnt(0)" ::: "memory");
    __builtin_amdgcn_sched_barrier(0);
    __builtin_amdgcn_s_setprio(1);
#pragma unroll
    for (int mi = 0; mi < 4; ++mi)
#pragma unroll
      for (int ni = 0; ni < 2; ++ni) {
        acc[1][mi][0][ni] = mfma16(av[mi][0], bv[ni][0], acc[1][mi][0][ni]);
        acc[1][mi][0][ni] = mfma16(av[mi][1], bv[ni][1], acc[1][mi][0][ni]);
      }
    __builtin_amdgcn_s_setprio(0);
    // tile boundary: retire next tile's staging (counted), then sync
    if (s2)      asm volatile("s_waitcnt vmcnt(4)" ::: "memory");
    else if (s1) asm volatile("s_waitcnt vmcnt(0)" ::: "memory");
    if (s1) __builtin_amdgcn_s_barrier();
  }

#pragma unroll
  for (int qr = 0; qr < 2; ++qr)
#pragma unroll
    for (int mi = 0; mi < 4; ++mi) {
      const int row0 = brow + wm * 64 + qr * 128 + mi * 16 + g * 4;
#pragma unroll
      for (int qc = 0; qc < 2; ++qc)
#pragma unroll
        for (int ni = 0; ni < 2; ++ni) {
          const int col = bcol + wn * 32 + qc * 128 + ni * 16 + r;
#pragma unroll
          for (int rr = 0; rr < 4; ++rr) {
            float v = acc[qr][mi][qc][ni][rr];
            if constexpr (sizeof(SC) == 2) C[(size_t)(row0 + rr) * N + col] = f2bf(v);
            else                           C[(size_t)(row0 + rr) * N + col] = v;
          }
        }
    }
}

// ---------------------------------------------------------------------------
// gemm256 (R8 structure): 256x128, BK=32, kept for gemm2 (N=1024).
// ---------------------------------------------------------------------------
template <typename SC>
__global__ __launch_bounds__(512, 4) void gemm256(const short* __restrict__ A,
                                                  const short* __restrict__ B,
                                                  SC* __restrict__ C,
                                                  int M, int N, int K) {
  __shared__ short lds[36864];

  const int tid  = threadIdx.x;
  const int lane = tid & 63;
  const int w    = tid >> 6;
  const int wm   = w >> 1;
  const int wn   = w & 1;
  const int g    = lane >> 4;
  const int r    = lane & 15;

  const int nbn = N >> 7;
  int bid = blockIdx.x;
  {
    const int cpx = gridDim.x >> 3;
    bid = (bid & 7) * cpx + (bid >> 3);
  }
  const int brow = (bid / nbn) << 8;
  const int bcol = (bid % nbn) << 7;
  const int NT   = K >> 5;

  const int lr = lane >> 2;
  const int lc = (lane & 3) * 8;

  f32x4 acc[4][4];
#pragma unroll
  for (int mi = 0; mi < 4; ++mi)
#pragma unroll
    for (int ni = 0; ni < 4; ++ni) acc[mi][ni] = (f32x4){0.f, 0.f, 0.f, 0.f};

  const short* gA0 = A + (size_t)(brow + 0   + w * 16 + lr) * K + lc;
  const short* gA1 = A + (size_t)(brow + 128 + w * 16 + lr) * K + lc;
  const short* gB0 = B + (size_t)(bcol +       w * 16 + lr) * K + lc;

  auto STAGE = [&](int buf, int t) {
    const int k0 = t << 5;
    short* ab = &lds[buf * 12288];
    short* bb = &lds[buf * 12288 + 8192];
    gload16(gA0 + k0, ab + (w * 16) * 32);
    gload16(gA1 + k0, ab + (128 + w * 16) * 32);
    gload16(gB0 + k0, bb + (w * 16) * 32);
  };

  STAGE(0, 0);
  STAGE(1, 1);
  asm volatile("s_waitcnt vmcnt(3)\n\ts_barrier" ::: "memory");

  for (int kt = 0; kt < NT; ++kt) {
    const int cur = kt % 3;
    const short* ab = &lds[cur * 12288];
    const short* bb = &lds[cur * 12288 + 8192];

    if (kt + 2 < NT) STAGE((kt + 2) % 3, kt + 2);

    short8 av[4], bvr[4];
#pragma unroll
    for (int mi = 0; mi < 4; ++mi)
      av[mi] = *(const short8*)(ab + (wm * 64 + mi * 16 + r) * 32 + g * 8);
#pragma unroll
    for (int ni = 0; ni < 2; ++ni)
      bvr[ni] = *(const short8*)(bb + (wn * 64 + ni * 16 + r) * 32 + g * 8);

    __builtin_amdgcn_s_setprio(1);
#pragma unroll
    for (int mi = 0; mi < 4; ++mi)
#pragma unroll
      for (int ni = 0; ni < 2; ++ni)
        acc[mi][ni] = mfma16(av[mi], bvr[ni], acc[mi][ni]);
    __builtin_amdgcn_s_setprio(0);

#pragma unroll
    for (int ni = 2; ni < 4; ++ni)
      bvr[ni] = *(const short8*)(bb + (wn * 64 + ni * 16 + r) * 32 + g * 8);

    __builtin_amdgcn_s_setprio(1);
#pragma unroll
    for (int mi = 0; mi < 4; ++mi)
#pragma unroll
      for (int ni = 2; ni < 4; ++ni)
        acc[mi][ni] = mfma16(av[mi], bvr[ni], acc[mi][ni]);
    __builtin_amdgcn_s_setprio(0);

    if (kt + 1 < NT) {
      if (kt + 2 < NT) asm volatile("s_waitcnt vmcnt(3)\n\ts_barrier" ::: "memory");
      else             asm volatile("s_waitcnt vmcnt(0)\n\ts_barrier" ::: "memory");
    }
  }

#pragma unroll
  for (int mi = 0; mi < 4; ++mi) {
    const int row0 = brow + wm * 64 + mi * 16 + g * 4;
#pragma unroll
    for (int ni = 0; ni < 4; ++ni) {
      const int col = bcol + wn * 64 + ni * 16 + r;
#pragma unroll
      for (int rr = 0; rr < 4; ++rr) {
        float v = acc[mi][ni][rr];
        if constexpr (sizeof(SC) == 2) C[(size_t)(row0 + rr) * N + col] = f2bf(v);
        else                           C[(size_t)(row0 + rr) * N + col] = v;
      }
    }
  }
}

// ---------------------------------------------------------------------------
// kv partial / reduce / attn: unchanged from R5-R9 (passed, absmax 32).
// ---------------------------------------------------------------------------
__global__ __launch_bounds__(256) void kv_partial(const short* __restrict__ qkv,
                                                  const float* __restrict__ beta,
                                                  short* __restrict__ partial) {
  const int bh = blockIdx.x / NCH;
  const int ch = blockIdx.x % NCH;
  const int b  = bh >> 4, h = bh & 15;

  __shared__ short kT[64][522];
  __shared__ short vT[64][522];

  const int tid  = threadIdx.x;
  const int lane = tid & 63;
  const int w    = tid >> 6;
  const int g    = lane >> 4;
  const int r    = lane & 15;

  const int srl  = tid >> 2;
  const int part = tid & 3;
  const size_t base = (size_t)b * SEQ * 3072 + (size_t)(ch * CHUNK) * 3072;
  const int kcol = DMODEL     + h * 64 + part * 16;
  const int vcol = 2 * DMODEL + h * 64 + part * 16;

#pragma unroll
  for (int ss = 0; ss < CHUNK; ss += 64) {
    const short* gk = qkv + base + (size_t)(ss + srl) * 3072 + kcol;
    const short* gv = qkv + base + (size_t)(ss + srl) * 3072 + vcol;
    short8 k0 = *(const short8*)gk;
    short8 k1 = *(const short8*)(gk + 8);
    short8 v0 = *(const short8*)gv;
    short8 v1 = *(const short8*)(gv + 8);
    const int sidx = ss + srl;
#pragma unroll
    for (int q = 0; q < 8; ++q) {
      kT[part * 16 + q][sidx]     = f2bf(fminf(fmaxf(bf2f(k0[q]) * 0.125f, -1.f), 1.f));
      kT[part * 16 + 8 + q][sidx] = f2bf(fminf(fmaxf(bf2f(k1[q]) * 0.125f, -1.f), 1.f));
      vT[part * 16 + q][sidx]     = v0[q];
      vT[part * 16 + 8 + q][sidx] = v1[q];
    }
  }
  __syncthreads();

  for (int m = 0; m < MD; ++m) {
    if (beta[h * MD + m] == 0.f) continue;

    f32x4 acc[4];
#pragma unroll
    for (int j = 0; j < 4; ++j) acc[j] = (f32x4){0.f, 0.f, 0.f, 0.f};

#pragma unroll 1
    for (int kt = 0; kt < CHUNK / 32; ++kt) {
      const int s0 = kt * 32 + g * 8;
      short8 af;
      if (m == 0) {
#pragma unroll
        for (int q = 0; q < 8; ++q) af[q] = (short)0x3F80;
      } else {
        short8 xs = *(const short8*)&kT[w * 16 + r][s0];
        float Tp[8], Tc[8];
#pragma unroll
        for (int q = 0; q < 8; ++q) { float xv = bf2f(xs[q]); Tp[q] = 1.f; Tc[q] = xv; }
        for (int mm = 1; mm < m; ++mm) {
#pragma unroll
          for (int q = 0; q < 8; ++q) {
            float xv = bf2f(xs[q]);
            float Tn = 2.f * xv * Tc[q] - Tp[q];
            Tp[q] = Tc[q]; Tc[q] = Tn;
          }
        }
#pragma unroll
        for (int q = 0; q < 8; ++q) af[q] = f2bf(Tc[q]);
      }
#pragma unroll
      for (int j = 0; j < 4; ++j) {
        short8 bfg = *(const short8*)&vT[j * 16 + r][s0];
        acc[j] = mfma16(af, bfg, acc[j]);
      }
    }

    short* po = partial + ((size_t)(bh * MD + m) * NCH + ch) * 4096;
#pragma unroll
    for (int j = 0; j < 4; ++j) {
      const int kd = w * 16 + g * 4;
      const int dv = j * 16 + r;
#pragma unroll
      for (int rr = 0; rr < 4; ++rr) po[(size_t)(kd + rr) * 64 + dv] = f2bf(acc[j][rr]);
    }
  }
}

__global__ __launch_bounds__(256) void kv_reduce(const short* __restrict__ partial,
                                                 const float* __restrict__ beta,
                                                 float* __restrict__ kv) {
  const int m  = blockIdx.x % MD;
  const int bh = blockIdx.x / MD;
  const int h  = bh & 15;
  if (beta[h * MD + m] == 0.f) return;

  const int tid = threadIdx.x;
  const short* src = partial + (size_t)(bh * MD + m) * NCH * 4096;
  float* dst = kv + (size_t)(bh * MD + m) * 4096;
#pragma unroll
  for (int e0 = 0; e0 < 4096; e0 += 256) {
    float s = 0.f;
#pragma unroll
    for (int c = 0; c < NCH; ++c) s += bf2f(src[c * 4096 + e0 + tid]);
    dst[e0 + tid] = s;
  }
}

__global__ __launch_bounds__(256) void attn_kernel(const short* __restrict__ qkv,
                                                   const float* __restrict__ beta,
                                                   const float* __restrict__ kv,
                                                   short* __restrict__ attn) {
  const int bid  = blockIdx.x;
  const int bh   = bid >> 4;
  const int sblk = bid & 15;
  const int b    = bh >> 4, h = bh & 15;

  __shared__ short kvT[64][744];

  const int tid  = threadIdx.x;
  const int lane = tid & 63;
  const int w    = tid >> 6;
  const int g    = lane >> 4;
  const int r    = lane & 15;

  float betav[MD];
#pragma unroll
  for (int mm = 0; mm < MD; ++mm) betav[mm] = beta[h * MD + mm];

  {
    int am = 0;
#pragma unroll
    for (int mm = 0; mm < MD; ++mm) {
      if (betav[mm] != 0.f) {
        const float* src = kv + (size_t)(bh * MD + mm) * 4096;
        for (int e = tid; e < 4096; e += 256) {
          const int kd = e >> 6, dv = e & 63;
          kvT[dv][am * 64 + kd] = f2bf(src[e]);
        }
        ++am;
      }
    }
  }
  __syncthreads();

  const size_t qbase = (size_t)b * SEQ * 3072 + (size_t)h * 64;

#pragma unroll 1
  for (int st = 0; st < 4; ++st) {
    const int srow = sblk * 256 + w * 64 + st * 16 + r;
    const short* gq = qkv + qbase + (size_t)srow * 3072;
    short8 q0 = *(const short8*)(gq + g * 8);
    short8 q1 = *(const short8*)(gq + 32 + g * 8);
    float x[16];
#pragma unroll
    for (int q = 0; q < 8; ++q) {
      x[q]     = fminf(fmaxf(bf2f(q0[q]) * 0.125f, -1.f), 1.f);
      x[8 + q] = fminf(fmaxf(bf2f(q1[q]) * 0.125f, -1.f), 1.f);
    }
    float Tp[16], Tc[16];
#pragma unroll
    for (int q = 0; q < 16; ++q) { Tp[q] = 1.f; Tc[q] = x[q]; }
    f32x4 acc[4];
#pragma unroll
    for (int j = 0; j < 4; ++j) acc[j] = (f32x4){0.f, 0.f, 0.f, 0.f};

    int am = 0;
#pragma unroll
    for (int mt = 0; mt < MD; ++mt) {
      if (mt >= 2) {
#pragma unroll
        for (int q = 0; q < 16; ++q) {
          float Tn = 2.f * x[q] * Tc[q] - Tp[q];
          Tp[q] = Tc[q]; Tc[q] = Tn;
        }
      }
      if (betav[mt] != 0.f) {
        const float bm = betav[mt];
        short8 a0, a1;
        if (mt == 0) {
          const short one = f2bf(bm);
#pragma unroll
          for (int q = 0; q < 8; ++q) { a0[q] = one; a1[q] = one; }
        } else {
#pragma unroll
          for (int q = 0; q < 8; ++q) {
            a0[q] = f2bf(bm * Tc[q]);
            a1[q] = f2bf(bm * Tc[8 + q]);
          }
        }
#pragma unroll
        for (int j = 0; j < 4; ++j) {
          short8 b0 = *(const short8*)&kvT[j * 16 + r][am * 64 + g * 8];
          acc[j] = mfma16(a0, b0, acc[j]);
          short8 b1 = *(const short8*)&kvT[j * 16 + r][am * 64 + 32 + g * 8];
          acc[j] = mfma16(a1, b1, acc[j]);
        }
        ++am;
      }
    }

#pragma unroll
    for (int j = 0; j < 4; ++j) {
      const int col = h * 64 + j * 16 + r;
#pragma unroll
      for (int rr = 0; rr < 4; ++rr) {
        const int sr = sblk * 256 + w * 64 + st * 16 + g * 4 + rr;
        attn[(size_t)(b * SEQ + sr) * DMODEL + col] = f2bf(acc[j][rr]);
      }
    }
  }
}

// ---------------------------------------------------------------------------
extern "C" void kernel_launch(void* const* d_in, const int* in_sizes, int n_in,
                              void* d_out, int out_size, void* d_ws, size_t ws_size,
                              hipStream_t stream) {
  const float* x     = (const float*)d_in[0];
  const float* w_in  = (const float*)d_in[1];
  const float* w_out = (const float*)d_in[2];
  const float* beta  = (const float*)d_in[3];
  float* out = (float*)d_out;

  char* ws = (char*)d_ws;
  short* qkv     = (short*)ws;                    // 50,331,648 B
  float* kvbuf   = (float*)(ws + 50331648);       //  5,767,168 B
  short* w_inb   = (short*)(ws + 56098816);       //  6,291,456 B
  short* w_outb  = (short*)(ws + 62390272);       //  2,097,152 B
  char*  regionU = ws + 64487424;                 // xb / partial / attn union
  short* xb      = (short*)regionU;
  short* partial = (short*)regionU;
  short* attn    = (short*)regionU;

  const int Mrows = BATCH * SEQ;  // 8192

  // 0) pre-convert f32 -> bf16
  to_bf16<<<dim3(8192), dim3(256), 0, stream>>>(x,     xb,     2097152);
  to_bf16<<<dim3(3072), dim3(256), 0, stream>>>(w_in,  w_inb,   786432);
  to_bf16<<<dim3(1024), dim3(256), 0, stream>>>(w_out, w_outb,  262144);

  // 1) qkv = x @ w_in^T  (8192 x 3072 x 1024): 32 x 12 = 384 blocks (256x256)
  gemm256sq<short><<<dim3((Mrows / 256) * (3 * DMODEL / 256)), dim3(512), 0, stream>>>(
      xb, w_inb, qkv, Mrows, 3 * DMODEL, DMODEL);

  // 2) kv partials over s-chunks, then reduce
  kv_partial<<<dim3(BATCH * NH * NCH), dim3(256), 0, stream>>>(qkv, beta, partial);
  kv_reduce<<<dim3(BATCH * NH * MD), dim3(256), 0, stream>>>(partial, beta, kvbuf);

  // 3) attn = sum_m beta_m T_m(q) @ kv_m
  attn_kernel<<<dim3(32 * 16), dim3(256), 0, stream>>>(qkv, beta, kvbuf, attn);

  // 4) out = attn @ w_out^T  (8192 x 1024 x 1024): 32 x 8 = 256 blocks (256x128)
  gemm256<float><<<dim3((Mrows / 256) * (DMODEL / 128)), dim3(512), 0, stream>>>(
      attn, w_outb, out, Mrows, DMODEL, DMODEL);
}

// Round 11
// 165.233 us; speedup vs baseline: 1.1325x; 1.1325x over previous
//
#include <hip/hip_runtime.h>
#include <hip/hip_bf16.h>

// ---------------------------------------------------------------------------
// CollapsedPBFA: x->(qkv GEMM)->cheb-kernelized linear attention->out GEMM
// R11: consolidation. gemm1+gemm2 = R8 kernel (best measured, 3 blocks/CU
//      exact). to_bf16 fused to one launch. kv path re-plumbed: partials
//      stored transposed [dv][kd], kv_reduce = flat bf16 sum, attn staging
//      vectorized (short8/b128). absmax tripwire: 32.0 expected.
// ---------------------------------------------------------------------------

#define SEQ    4096
#define BATCH  2
#define DMODEL 1024
#define NH     16
#define DH     64
#define MD     11
#define NCH    8
#define CHUNK  512   // SEQ / NCH

typedef __attribute__((ext_vector_type(8)))  short  short8;
typedef __attribute__((ext_vector_type(4)))  short  s16x4;
typedef __attribute__((ext_vector_type(8)))  __bf16 bf16x8;
typedef __attribute__((ext_vector_type(4)))  float  f32x4;

__device__ __forceinline__ short f2bf(float f) {
  union { float f; unsigned u; } c; c.f = f;
  unsigned r = c.u + 0x7FFFu + ((c.u >> 16) & 1u);
  return (short)(r >> 16);
}
__device__ __forceinline__ float bf2f(short h) {
  union { unsigned u; float f; } c; c.u = ((unsigned)(unsigned short)h) << 16;
  return c.f;
}

__device__ __forceinline__ f32x4 mfma16(short8 a, short8 b, f32x4 c) {
  return __builtin_amdgcn_mfma_f32_16x16x32_bf16(
      __builtin_bit_cast(bf16x8, a), __builtin_bit_cast(bf16x8, b), c, 0, 0, 0);
}

typedef const __attribute__((address_space(1))) void* gvp;
typedef __attribute__((address_space(3))) void* lvp;
// Async global->LDS, 16B per lane: lane i lands at (uniform dst) + 16*i.
__device__ __forceinline__ void gload16(const void* g, void* l) {
  __builtin_amdgcn_global_load_lds((gvp)g, (lvp)l, 16, 0, 0);
}

// ---------------------------------------------------------------------------
// fused f32 -> bf16 convert for x, w_in, w_out in one launch.
// grid = (2097152 + 786432 + 262144) f32x4 quads / 256 = 12288 blocks.
// ---------------------------------------------------------------------------
__global__ __launch_bounds__(256) void to_bf16_all(const float* __restrict__ x,
                                                   const float* __restrict__ w_in,
                                                   const float* __restrict__ w_out,
                                                   short* __restrict__ xb,
                                                   short* __restrict__ w_inb,
                                                   short* __restrict__ w_outb) {
  int i = blockIdx.x * 256 + threadIdx.x;
  const float* src; short* dst; int off;
  if (i < 2097152)      { src = x;     dst = xb;     off = i; }
  else if (i < 2883584) { src = w_in;  dst = w_inb;  off = i - 2097152; }
  else                  { src = w_out; dst = w_outb; off = i - 2883584; }
  f32x4 v = ((const f32x4*)src)[off];
  s16x4 o;
#pragma unroll
  for (int q = 0; q < 4; ++q) o[q] = f2bf(v[q]);
  ((s16x4*)dst)[off] = o;
}

// ---------------------------------------------------------------------------
// GEMM (R8 structure, best measured): C[M][N] = A[M][K] * B[N][K]^T, bf16.
// Tile 256x128, BK=32, 512 threads = 8 waves, per-wave 64x64. 3-buffer LDS
// rotation (72KB -> 2 blocks/CU), distance-2 staging, vmcnt(3) + 1 barrier
// per tile. Requires: M%256==0, N%128==0, K%32==0, NT>=3, grid%8==0.
// ---------------------------------------------------------------------------
template <typename SC>
__global__ __launch_bounds__(512, 4) void gemm256(const short* __restrict__ A,
                                                  const short* __restrict__ B,
                                                  SC* __restrict__ C,
                                                  int M, int N, int K) {
  __shared__ short lds[36864];

  const int tid  = threadIdx.x;
  const int lane = tid & 63;
  const int w    = tid >> 6;        // 0..7
  const int wm   = w >> 1;          // 0..3 (64-row strip)
  const int wn   = w & 1;           // 0..1 (64-col strip)
  const int g    = lane >> 4;       // 0..3
  const int r    = lane & 15;       // 0..15

  const int nbn = N >> 7;
  int bid = blockIdx.x;
  {  // bijective XCD swizzle (gridDim.x % 8 == 0 for our shapes)
    const int cpx = gridDim.x >> 3;
    bid = (bid & 7) * cpx + (bid >> 3);
  }
  const int brow = (bid / nbn) << 8;
  const int bcol = (bid % nbn) << 7;
  const int NT   = K >> 5;

  const int lr = lane >> 2;        // 0..15 row within strip
  const int lc = (lane & 3) * 8;   // 16B chunk within row (shorts)

  f32x4 acc[4][4];
#pragma unroll
  for (int mi = 0; mi < 4; ++mi)
#pragma unroll
    for (int ni = 0; ni < 4; ++ni) acc[mi][ni] = (f32x4){0.f, 0.f, 0.f, 0.f};

  const short* gA0 = A + (size_t)(brow + 0   + w * 16 + lr) * K + lc;
  const short* gA1 = A + (size_t)(brow + 128 + w * 16 + lr) * K + lc;
  const short* gB0 = B + (size_t)(bcol +       w * 16 + lr) * K + lc;

  auto STAGE = [&](int buf, int t) {
    const int k0 = t << 5;
    short* ab = &lds[buf * 12288];
    short* bb = &lds[buf * 12288 + 8192];
    gload16(gA0 + k0, ab + (w * 16) * 32);
    gload16(gA1 + k0, ab + (128 + w * 16) * 32);
    gload16(gB0 + k0, bb + (w * 16) * 32);
  };

  STAGE(0, 0);
  STAGE(1, 1);
  asm volatile("s_waitcnt vmcnt(3)\n\ts_barrier" ::: "memory");

  for (int kt = 0; kt < NT; ++kt) {
    const int cur = kt % 3;
    const short* ab = &lds[cur * 12288];
    const short* bb = &lds[cur * 12288 + 8192];

    if (kt + 2 < NT) STAGE((kt + 2) % 3, kt + 2);

    short8 av[4], bv[4];
#pragma unroll
    for (int mi = 0; mi < 4; ++mi)
      av[mi] = *(const short8*)(ab + (wm * 64 + mi * 16 + r) * 32 + g * 8);
#pragma unroll
    for (int ni = 0; ni < 2; ++ni)
      bv[ni] = *(const short8*)(bb + (wn * 64 + ni * 16 + r) * 32 + g * 8);

    __builtin_amdgcn_s_setprio(1);
#pragma unroll
    for (int mi = 0; mi < 4; ++mi)
#pragma unroll
      for (int ni = 0; ni < 2; ++ni)
        acc[mi][ni] = mfma16(av[mi], bv[ni], acc[mi][ni]);
    __builtin_amdgcn_s_setprio(0);

#pragma unroll
    for (int ni = 2; ni < 4; ++ni)
      bv[ni] = *(const short8*)(bb + (wn * 64 + ni * 16 + r) * 32 + g * 8);

    __builtin_amdgcn_s_setprio(1);
#pragma unroll
    for (int mi = 0; mi < 4; ++mi)
#pragma unroll
      for (int ni = 2; ni < 4; ++ni)
        acc[mi][ni] = mfma16(av[mi], bv[ni], acc[mi][ni]);
    __builtin_amdgcn_s_setprio(0);

    if (kt + 1 < NT) {
      if (kt + 2 < NT) asm volatile("s_waitcnt vmcnt(3)\n\ts_barrier" ::: "memory");
      else             asm volatile("s_waitcnt vmcnt(0)\n\ts_barrier" ::: "memory");
    }
  }

#pragma unroll
  for (int mi = 0; mi < 4; ++mi) {
    const int row0 = brow + wm * 64 + mi * 16 + g * 4;
#pragma unroll
    for (int ni = 0; ni < 4; ++ni) {
      const int col = bcol + wn * 64 + ni * 16 + r;
#pragma unroll
      for (int rr = 0; rr < 4; ++rr) {
        float v = acc[mi][ni][rr];
        if constexpr (sizeof(SC) == 2) C[(size_t)(row0 + rr) * N + col] = f2bf(v);
        else                           C[(size_t)(row0 + rr) * N + col] = v;
      }
    }
  }
}

// ---------------------------------------------------------------------------
// kv partial: block = (bh, chunk of 512 s-rows). Stage k~/v transposed into
// chunk-resident LDS once, loop active m over the resident tile.
// R11: partials written TRANSPOSED, po[dv*64+kd] = KV[kd][dv] (bf16), so the
// downstream reduce + attn staging are flat and coalesced.
// ---------------------------------------------------------------------------
__global__ __launch_bounds__(256) void kv_partial(const short* __restrict__ qkv,
                                                  const float* __restrict__ beta,
                                                  short* __restrict__ partial) {
  const int bh = blockIdx.x / NCH;
  const int ch = blockIdx.x % NCH;
  const int b  = bh >> 4, h = bh & 15;

  __shared__ short kT[64][522];   // [kd][s], stride 261 dw
  __shared__ short vT[64][522];   // [dv][s]

  const int tid  = threadIdx.x;
  const int lane = tid & 63;
  const int w    = tid >> 6;
  const int g    = lane >> 4;
  const int r    = lane & 15;

  const int srl  = tid >> 2;
  const int part = tid & 3;
  const size_t base = (size_t)b * SEQ * 3072 + (size_t)(ch * CHUNK) * 3072;
  const int kcol = DMODEL     + h * 64 + part * 16;
  const int vcol = 2 * DMODEL + h * 64 + part * 16;

#pragma unroll
  for (int ss = 0; ss < CHUNK; ss += 64) {
    const short* gk = qkv + base + (size_t)(ss + srl) * 3072 + kcol;
    const short* gv = qkv + base + (size_t)(ss + srl) * 3072 + vcol;
    short8 k0 = *(const short8*)gk;
    short8 k1 = *(const short8*)(gk + 8);
    short8 v0 = *(const short8*)gv;
    short8 v1 = *(const short8*)(gv + 8);
    const int sidx = ss + srl;
#pragma unroll
    for (int q = 0; q < 8; ++q) {
      kT[part * 16 + q][sidx]     = f2bf(fminf(fmaxf(bf2f(k0[q]) * 0.125f, -1.f), 1.f));
      kT[part * 16 + 8 + q][sidx] = f2bf(fminf(fmaxf(bf2f(k1[q]) * 0.125f, -1.f), 1.f));
      vT[part * 16 + q][sidx]     = v0[q];
      vT[part * 16 + 8 + q][sidx] = v1[q];
    }
  }
  __syncthreads();

  for (int m = 0; m < MD; ++m) {
    if (beta[h * MD + m] == 0.f) continue;

    f32x4 acc[4];
#pragma unroll
    for (int j = 0; j < 4; ++j) acc[j] = (f32x4){0.f, 0.f, 0.f, 0.f};

#pragma unroll 1
    for (int kt = 0; kt < CHUNK / 32; ++kt) {
      const int s0 = kt * 32 + g * 8;
      short8 af;
      if (m == 0) {
#pragma unroll
        for (int q = 0; q < 8; ++q) af[q] = (short)0x3F80;
      } else {
        short8 xs = *(const short8*)&kT[w * 16 + r][s0];
        float Tp[8], Tc[8];
#pragma unroll
        for (int q = 0; q < 8; ++q) { float xv = bf2f(xs[q]); Tp[q] = 1.f; Tc[q] = xv; }
        for (int mm = 1; mm < m; ++mm) {
#pragma unroll
          for (int q = 0; q < 8; ++q) {
            float xv = bf2f(xs[q]);
            float Tn = 2.f * xv * Tc[q] - Tp[q];
            Tp[q] = Tc[q]; Tc[q] = Tn;
          }
        }
#pragma unroll
        for (int q = 0; q < 8; ++q) af[q] = f2bf(Tc[q]);
      }
#pragma unroll
      for (int j = 0; j < 4; ++j) {
        short8 bfg = *(const short8*)&vT[j * 16 + r][s0];
        acc[j] = mfma16(af, bfg, acc[j]);
      }
    }

    // transposed epilogue: po[dv][kd] = KV[kd][dv]
    short* po = partial + ((size_t)(bh * MD + m) * NCH + ch) * 4096;
#pragma unroll
    for (int j = 0; j < 4; ++j) {
      const int dv = j * 16 + r;
      const int kd = w * 16 + g * 4;
#pragma unroll
      for (int rr = 0; rr < 4; ++rr) po[(size_t)dv * 64 + kd + rr] = f2bf(acc[j][rr]);
    }
  }
}

// ---------------------------------------------------------------------------
// reduce partials (flat, coalesced) -> kvt bf16 [bh][m][dv*64+kd].
// ---------------------------------------------------------------------------
__global__ __launch_bounds__(256) void kv_reduce(const short* __restrict__ partial,
                                                 const float* __restrict__ beta,
                                                 short* __restrict__ kvt) {
  const int m  = blockIdx.x % MD;
  const int bh = blockIdx.x / MD;
  const int h  = bh & 15;
  if (beta[h * MD + m] == 0.f) return;

  const int t = threadIdx.x;
  const short* src = partial + (size_t)(bh * MD + m) * NCH * 4096;
  short* dst = kvt + (size_t)(bh * MD + m) * 4096;

  float s[16];
#pragma unroll
  for (int q = 0; q < 16; ++q) s[q] = 0.f;
#pragma unroll
  for (int c = 0; c < NCH; ++c) {
    short8 a0 = *(const short8*)&src[c * 4096 + t * 16];
    short8 a1 = *(const short8*)&src[c * 4096 + t * 16 + 8];
#pragma unroll
    for (int q = 0; q < 8; ++q) { s[q] += bf2f(a0[q]); s[8 + q] += bf2f(a1[q]); }
  }
  short8 o0, o1;
#pragma unroll
  for (int q = 0; q < 8; ++q) { o0[q] = f2bf(s[q]); o1[q] = f2bf(s[8 + q]); }
  *(short8*)&dst[t * 16]     = o0;
  *(short8*)&dst[t * 16 + 8] = o1;
}

// ---------------------------------------------------------------------------
// attn: per (b,h,256 s-rows); kv staged (vectorized copy) bf16 in LDS.
// ---------------------------------------------------------------------------
__global__ __launch_bounds__(256) void attn_kernel(const short* __restrict__ qkv,
                                                   const float* __restrict__ beta,
                                                   const short* __restrict__ kvt,
                                                   short* __restrict__ attn) {
  const int bid  = blockIdx.x;
  const int bh   = bid >> 4;
  const int sblk = bid & 15;
  const int b    = bh >> 4, h = bh & 15;

  __shared__ short kvT[64][744];

  const int tid  = threadIdx.x;
  const int lane = tid & 63;
  const int w    = tid >> 6;
  const int g    = lane >> 4;
  const int r    = lane & 15;

  float betav[MD];
#pragma unroll
  for (int mm = 0; mm < MD; ++mm) betav[mm] = beta[h * MD + mm];

  // stage active kv slices: flat vectorized copy (src already [dv][kd])
  {
    const int dv  = tid >> 2;
    const int kd0 = (tid & 3) * 16;
    int am = 0;
#pragma unroll
    for (int mm = 0; mm < MD; ++mm) {
      if (betav[mm] != 0.f) {
        const short* src = kvt + (size_t)(bh * MD + mm) * 4096 + dv * 64 + kd0;
        short8 s0 = *(const short8*)src;
        short8 s1 = *(const short8*)(src + 8);
        *(short8*)&kvT[dv][am * 64 + kd0]     = s0;
        *(short8*)&kvT[dv][am * 64 + kd0 + 8] = s1;
        ++am;
      }
    }
  }
  __syncthreads();

  const size_t qbase = (size_t)b * SEQ * 3072 + (size_t)h * 64;

#pragma unroll 1
  for (int st = 0; st < 4; ++st) {
    const int srow = sblk * 256 + w * 64 + st * 16 + r;
    const short* gq = qkv + qbase + (size_t)srow * 3072;
    short8 q0 = *(const short8*)(gq + g * 8);
    short8 q1 = *(const short8*)(gq + 32 + g * 8);
    float x[16];
#pragma unroll
    for (int q = 0; q < 8; ++q) {
      x[q]     = fminf(fmaxf(bf2f(q0[q]) * 0.125f, -1.f), 1.f);
      x[8 + q] = fminf(fmaxf(bf2f(q1[q]) * 0.125f, -1.f), 1.f);
    }
    float Tp[16], Tc[16];
#pragma unroll
    for (int q = 0; q < 16; ++q) { Tp[q] = 1.f; Tc[q] = x[q]; }
    f32x4 acc[4];
#pragma unroll
    for (int j = 0; j < 4; ++j) acc[j] = (f32x4){0.f, 0.f, 0.f, 0.f};

    int am = 0;
#pragma unroll
    for (int mt = 0; mt < MD; ++mt) {
      if (mt >= 2) {
#pragma unroll
        for (int q = 0; q < 16; ++q) {
          float Tn = 2.f * x[q] * Tc[q] - Tp[q];
          Tp[q] = Tc[q]; Tc[q] = Tn;
        }
      }
      if (betav[mt] != 0.f) {
        const float bm = betav[mt];
        short8 a0, a1;
        if (mt == 0) {
          const short one = f2bf(bm);
#pragma unroll
          for (int q = 0; q < 8; ++q) { a0[q] = one; a1[q] = one; }
        } else {
#pragma unroll
          for (int q = 0; q < 8; ++q) {
            a0[q] = f2bf(bm * Tc[q]);
            a1[q] = f2bf(bm * Tc[8 + q]);
          }
        }
#pragma unroll
        for (int j = 0; j < 4; ++j) {
          short8 b0 = *(const short8*)&kvT[j * 16 + r][am * 64 + g * 8];
          acc[j] = mfma16(a0, b0, acc[j]);
          short8 b1 = *(const short8*)&kvT[j * 16 + r][am * 64 + 32 + g * 8];
          acc[j] = mfma16(a1, b1, acc[j]);
        }
        ++am;
      }
    }

#pragma unroll
    for (int j = 0; j < 4; ++j) {
      const int col = h * 64 + j * 16 + r;
#pragma unroll
      for (int rr = 0; rr < 4; ++rr) {
        const int sr = sblk * 256 + w * 64 + st * 16 + g * 4 + rr;
        attn[(size_t)(b * SEQ + sr) * DMODEL + col] = f2bf(acc[j][rr]);
      }
    }
  }
}

// ---------------------------------------------------------------------------
extern "C" void kernel_launch(void* const* d_in, const int* in_sizes, int n_in,
                              void* d_out, int out_size, void* d_ws, size_t ws_size,
                              hipStream_t stream) {
  const float* x     = (const float*)d_in[0];
  const float* w_in  = (const float*)d_in[1];
  const float* w_out = (const float*)d_in[2];
  const float* beta  = (const float*)d_in[3];
  float* out = (float*)d_out;

  char* ws = (char*)d_ws;
  short* qkv     = (short*)ws;                    // 50,331,648 B
  short* kvt     = (short*)(ws + 50331648);       //  2,883,584 B (bf16, [dv][kd])
  short* w_inb   = (short*)(ws + 56098816);       //  6,291,456 B
  short* w_outb  = (short*)(ws + 62390272);       //  2,097,152 B
  char*  regionU = ws + 64487424;                 // xb / partial / attn union
  short* xb      = (short*)regionU;
  short* partial = (short*)regionU;
  short* attn    = (short*)regionU;

  const int Mrows = BATCH * SEQ;  // 8192

  // 0) pre-convert f32 -> bf16 (single fused launch)
  to_bf16_all<<<dim3(12288), dim3(256), 0, stream>>>(x, w_in, w_out, xb, w_inb, w_outb);

  // 1) qkv = x @ w_in^T        (8192 x 3072 x 1024): 32 x 24 = 768 blocks
  gemm256<short><<<dim3((Mrows / 256) * (3 * DMODEL / 128)), dim3(512), 0, stream>>>(
      xb, w_inb, qkv, Mrows, 3 * DMODEL, DMODEL);

  // 2) kv partials over s-chunks, then flat reduce -> kvt (bf16 transposed)
  kv_partial<<<dim3(BATCH * NH * NCH), dim3(256), 0, stream>>>(qkv, beta, partial);
  kv_reduce<<<dim3(BATCH * NH * MD), dim3(256), 0, stream>>>(partial, beta, kvt);

  // 3) attn = sum_m beta_m T_m(q) @ kv_m
  attn_kernel<<<dim3(32 * 16), dim3(256), 0, stream>>>(qkv, beta, kvt, attn);

  // 4) out = attn @ w_out^T    (8192 x 1024 x 1024): 32 x 8 = 256 blocks
  gemm256<float><<<dim3((Mrows / 256) * (DMODEL / 128)), dim3(512), 0, stream>>>(
      attn, w_outb, out, Mrows, DMODEL, DMODEL);
}